// Round 3
// baseline (758.427 us; speedup 1.0000x reference)
//
#include <hip/hip_runtime.h>
#include <cmath>

#define N_TOK 4096
#define DDIM 1024
#define FDIM 4096
#define NEXP 8
#define MAXT 40                 // 256-row tiles; worst case sum ceil(c_e/256) = 39
#define MAXROWS (MAXT * 256)

typedef __attribute__((ext_vector_type(4))) float f32x4;
typedef __attribute__((ext_vector_type(8))) __bf16 bf16x8;
typedef __attribute__((ext_vector_type(4))) unsigned short us4;
typedef __attribute__((ext_vector_type(8))) unsigned short us8;

__device__ __forceinline__ unsigned short f2bf(float f) {
  unsigned u = __builtin_bit_cast(unsigned, f);
  u += 0x7FFFu + ((u >> 16) & 1u);
  return (unsigned short)(u >> 16);
}

__device__ __forceinline__ void gload16(const void* g, void* l) {
  __builtin_amdgcn_global_load_lds(
      (const __attribute__((address_space(1))) unsigned int*)g,
      (__attribute__((address_space(3))) unsigned int*)l, 16, 0, 0);
}

// m204 bijective XCD remap
__device__ __forceinline__ int xcd_remap(int h, int nwg) {
  int q = nwg >> 3, r = nwg & 7;
  int xcd = h & 7, o = h >> 3;
  return (xcd < r ? xcd * (q + 1) : r * (q + 1) + (xcd - r) * q) + o;
}

// ---------------- router ----------------
__global__ __launch_bounds__(64) void router_kernel(
    const float* __restrict__ x, const float* __restrict__ wg,
    float* __restrict__ probs, int* __restrict__ eids, float* __restrict__ ewts) {
  int n = blockIdx.x;
  int t = threadIdx.x;
  const float* xr = x + (size_t)n * DDIM;
  float acc[8] = {0, 0, 0, 0, 0, 0, 0, 0};
  for (int k = t; k < DDIM; k += 64) {
    float xv = xr[k];
    const float* wr = wg + k * 8;
#pragma unroll
    for (int e = 0; e < 8; e++) acc[e] = fmaf(xv, wr[e], acc[e]);
  }
#pragma unroll
  for (int off = 32; off > 0; off >>= 1) {
#pragma unroll
    for (int e = 0; e < 8; e++) acc[e] += __shfl_xor(acc[e], off, 64);
  }
  if (t == 0) {
    float mx = acc[0];
#pragma unroll
    for (int e = 1; e < 8; e++) mx = fmaxf(mx, acc[e]);
    float p[8], s = 0.f;
#pragma unroll
    for (int e = 0; e < 8; e++) { p[e] = expf(acc[e] - mx); s += p[e]; }
    float inv = 1.f / s;
#pragma unroll
    for (int e = 0; e < 8; e++) { p[e] *= inv; probs[n * 8 + e] = p[e]; }
    int i0 = 0;
#pragma unroll
    for (int e = 1; e < 8; e++) if (p[e] > p[i0]) i0 = e;
    int i1 = (i0 == 0) ? 1 : 0;
#pragma unroll
    for (int e = 0; e < 8; e++) if (e != i0 && p[e] > p[i1]) i1 = e;
    float sw = p[i0] + p[i1];
    eids[n * 2] = i0; eids[n * 2 + 1] = i1;
    ewts[n * 2] = p[i0] / sw; ewts[n * 2 + 1] = p[i1] / sw;
  }
}

// ---------------- plan (256-row tiles) ----------------
// meta: [0..8) cnt, [8..16) cursor, [16..24) tileBase(256), [24..96) tileExpert, [96] total
__global__ __launch_bounds__(256) void plan_kernel(
    const float* __restrict__ probs, const int* __restrict__ eids,
    float* __restrict__ aux_out, int* __restrict__ meta) {
  __shared__ float pl[256][8];
  __shared__ int cl[256][8];
  __shared__ float ps2[8];
  __shared__ int cn2[8];
  int t = threadIdx.x;
  float pa[8] = {0, 0, 0, 0, 0, 0, 0, 0};
  int ca[8] = {0, 0, 0, 0, 0, 0, 0, 0};
  for (int n = t; n < N_TOK; n += 256) {
#pragma unroll
    for (int e = 0; e < 8; e++) pa[e] += probs[n * 8 + e];
    ca[eids[n * 2]]++; ca[eids[n * 2 + 1]]++;
  }
#pragma unroll
  for (int e = 0; e < 8; e++) { pl[t][e] = pa[e]; cl[t][e] = ca[e]; }
  __syncthreads();
  if (t < 8) {
    float s = 0; int c = 0;
    for (int i = 0; i < 256; i++) { s += pl[i][t]; c += cl[i][t]; }
    ps2[t] = s; cn2[t] = c;
  }
  __syncthreads();
  if (t == 0) {
    int tb = 0; float aux = 0.f;
    for (int e = 0; e < 8; e++) {
      int c = cn2[e];
      meta[e] = c; meta[8 + e] = 0; meta[16 + e] = tb;
      int tiles = (c + 255) >> 8;
      for (int i = 0; i < tiles; i++) meta[24 + tb + i] = e;
      tb += tiles;
      aux += ((float)c / (float)(N_TOK * 2)) * (ps2[e] / (float)N_TOK);
    }
    meta[96] = tb;
    *aux_out = 0.01f * 8.f * aux;
  }
}

// ---------------- scatter ----------------
__global__ __launch_bounds__(256) void scatter_kernel(
    const int* __restrict__ eids, const float* __restrict__ ewts,
    int* __restrict__ meta, int* __restrict__ perm, float* __restrict__ wgt) {
  int n = blockIdx.x * 256 + threadIdx.x;
  if (n >= N_TOK) return;
#pragma unroll
  for (int s = 0; s < 2; s++) {
    int e = eids[n * 2 + s];
    int pos = atomicAdd(&meta[8 + e], 1);
    int row = (meta[16 + e] << 8) + pos;
    perm[row] = n;
    wgt[row] = ewts[n * 2 + s];
  }
}

// ---------------- x f32 -> bf16 ----------------
__global__ __launch_bounds__(256) void convert_x_kernel(
    const float* __restrict__ x, unsigned short* __restrict__ xb) {
  int i = blockIdx.x * 256 + threadIdx.x;
  f32x4 v = ((const f32x4*)x)[i];
  us4 o = {f2bf(v[0]), f2bf(v[1]), f2bf(v[2]), f2bf(v[3])};
  ((us4*)xb)[i] = o;
}

// ---------------- transpose + convert f32[R][C] -> bf16[C][R] ----------------
__global__ __launch_bounds__(256) void transpose_conv(
    const float* __restrict__ src, unsigned short* __restrict__ dst, int R, int C) {
  __shared__ unsigned short tile[64 * 64];
  size_t eoff = (size_t)blockIdx.z * (size_t)R * (size_t)C;
  src += eoff; dst += eoff;
  int c0 = blockIdx.x << 6, r0 = blockIdx.y << 6;
  int t = threadIdx.x;
  int rl = (t >> 4) << 2;
  int cl = (t & 15) << 2;
  f32x4 v[4];
#pragma unroll
  for (int i = 0; i < 4; i++)
    v[i] = *(const f32x4*)(src + (size_t)(r0 + rl + i) * C + c0 + cl);
#pragma unroll
  for (int u = 0; u < 4; u++) {
    int c = cl + u;
    us4 o = {f2bf(v[0][u]), f2bf(v[1][u]), f2bf(v[2][u]), f2bf(v[3][u])};
    unsigned byteoff = (unsigned)c * 128 + ((((unsigned)(rl >> 3)) ^ (unsigned)(c & 7)) << 4) + (unsigned)(rl & 7) * 2;
    *(us4*)((char*)tile + byteoff) = o;
  }
  __syncthreads();
#pragma unroll
  for (int p = 0; p < 2; p++) {
    int id = t + p * 256;
    int c = id >> 3, q = id & 7;
    unsigned byteoff = (unsigned)c * 128 + (((unsigned)q ^ (unsigned)(c & 7)) << 4);
    us8 val = *(const us8*)((const char*)tile + byteoff);
    *(us8*)(dst + (size_t)(c0 + c) * R + r0 + q * 8) = val;
  }
}

// ---------------- 256x256 8-phase grouped GEMM, BK=64, 8 waves ----------------
// per wave: C = 128x64 (wm in {0,1} x 64*wn), acc[8][4] f32x4.
// LDS: [buf 2][ A 256x64 | B 256x64 ] bf16, XOR-swizzled via pre-swizzled source.
// MODE 1: gelu->bf16 Hout.  MODE 2: weighted f32 atomic scatter into Out.
#define MFMA_Q(MH, NH, BF)                                                     \
  _Pragma("unroll") for (int mf = 0; mf < 4; mf++)                             \
  _Pragma("unroll") for (int nf = 0; nf < 2; nf++)                             \
  _Pragma("unroll") for (int kss = 0; kss < 2; kss++)                          \
    acc[(MH)*4 + mf][(NH)*2 + nf] = __builtin_amdgcn_mfma_f32_16x16x32_bf16(   \
        af[mf][kss], BF[nf][kss], acc[(MH)*4 + mf][(NH)*2 + nf], 0, 0, 0);

#define READ_A(MH, BC)                                                         \
  _Pragma("unroll") for (int mf = 0; mf < 4; mf++)                             \
  _Pragma("unroll") for (int kss = 0; kss < 2; kss++) {                        \
    int m = wm * 128 + (MH)*64 + mf * 16 + ln;                                 \
    int q = kss * 4 + g;                                                       \
    af[mf][kss] = *(const bf16x8*)((BC) + m * 128 + ((q ^ (m & 7)) << 4));     \
  }

#define READ_B(NH, DST, BC)                                                    \
  _Pragma("unroll") for (int nf = 0; nf < 2; nf++)                             \
  _Pragma("unroll") for (int kss = 0; kss < 2; kss++) {                        \
    int nn = wn * 64 + (NH)*32 + nf * 16 + ln;                                 \
    int q = kss * 4 + g;                                                       \
    DST[nf][kss] = *(const bf16x8*)((BC) + 32768 + nn * 128 + ((q ^ (nn & 7)) << 4)); \
  }

#define LGKM0_FENCE                                                            \
  asm volatile("s_waitcnt lgkmcnt(0)" ::: "memory");                           \
  __builtin_amdgcn_sched_barrier(0);

template <int K, int KSLICES, int NPANELS, bool GATHER, int MODE>
__global__ __launch_bounds__(512, 2) void gemm8p(
    const unsigned short* __restrict__ A,   // bf16 rows, stride K
    const unsigned short* __restrict__ Bt,  // bf16 [E][NB][K]
    unsigned short* __restrict__ Hout,
    float* __restrict__ Out,
    const int* __restrict__ perm, const float* __restrict__ wgt,
    const int* __restrict__ tileExpert, const int* __restrict__ totalTiles,
    int NB) {
  constexpr int NWG = MAXT * NPANELS * KSLICES;
  constexpr int KB = K / KSLICES;
  constexpr int NT = KB / 64;
  __shared__ unsigned short smem[131072 / 2];  // 128 KiB: [buf][A 32K | B 32K]

  int L = xcd_remap((int)blockIdx.x, NWG);
  constexpr int PER = NPANELS * KSLICES;
  int mt = L / PER;
  int rest = L % PER;
  int nt = rest % NPANELS;
  int ks = rest / NPANELS;
  if (mt >= *totalTiles) return;
  int e = tileExpert[mt];
  int m0 = mt << 8;
  int n0 = nt << 8;
  int k0 = ks * KB;

  int t = threadIdx.x;
  int wid = t >> 6, lane = t & 63;
  int g = lane >> 4, ln = lane & 15;
  int wm = wid >> 2, wn = wid & 3;

  // stage sources: halves 0=A[0:128) 1=B[0:128) 2=B[128:256) 3=A[128:256)
  // per (half, l): wave-uniform LDS byte offset + per-lane global src
  const unsigned short* src[4][2];
  unsigned loff[4][2];
  {
    int kc = lane & 7;
#pragma unroll
    for (int l = 0; l < 2; l++) {
      int r8 = (wid * 2 + l) * 8 + (lane >> 3);
      unsigned rb = (unsigned)(wid * 2 + l) * 1024;
      int swz = ((kc ^ (r8 & 7)) << 3);
      // half0: A rows [0,128)
      {
        int rl = r8;
        int grow = GATHER ? perm[m0 + rl] : (m0 + rl);
        src[0][l] = A + (size_t)grow * K + k0 + swz;
        loff[0][l] = rb;
      }
      // half3: A rows [128,256)
      {
        int rl = 128 + r8;
        int grow = GATHER ? perm[m0 + rl] : (m0 + rl);
        src[3][l] = A + (size_t)grow * K + k0 + swz;
        loff[3][l] = 16384u + rb;
      }
      // half1: B rows [0,128)
      src[1][l] = Bt + ((size_t)e * NB + n0 + r8) * K + k0 + swz;
      loff[1][l] = 32768u + rb;
      // half2: B rows [128,256)
      src[2][l] = Bt + ((size_t)e * NB + n0 + 128 + r8) * K + k0 + swz;
      loff[2][l] = 32768u + 16384u + rb;
    }
  }

  f32x4 acc[8][4];
#pragma unroll
  for (int a = 0; a < 8; a++)
#pragma unroll
    for (int b = 0; b < 4; b++) acc[a][b] = (f32x4){0.f, 0.f, 0.f, 0.f};

  bf16x8 af[4][2], b0f[2][2], b1f[2][2];
  char* smb = (char*)smem;

  // prologue: stage K-tile 0 into buf 0
#pragma unroll
  for (int h = 0; h < 4; h++)
#pragma unroll
    for (int l = 0; l < 2; l++) gload16(src[h][l], smb + loff[h][l]);
  asm volatile("s_waitcnt vmcnt(0)" ::: "memory");
  __builtin_amdgcn_s_barrier();

  for (int tt = 0; tt < NT; ++tt) {
    const char* bc = smb + (tt & 1) * 65536;
    char* bd = smb + ((tt & 1) ^ 1) * 65536;
    bool pre = (tt + 1) < NT;
    int ko = (tt + 1) * 64;

    // ---- phase 0: quadrant (0,0); prefetch halves 0,1 of next tile
    READ_A(0, bc)
    READ_B(0, b0f, bc)
    if (pre) {
      gload16(src[0][0] + ko, bd + loff[0][0]);
      gload16(src[0][1] + ko, bd + loff[0][1]);
      gload16(src[1][0] + ko, bd + loff[1][0]);
      gload16(src[1][1] + ko, bd + loff[1][1]);
    }
    __builtin_amdgcn_s_barrier();
    LGKM0_FENCE
    __builtin_amdgcn_s_setprio(1);
    MFMA_Q(0, 0, b0f)
    __builtin_amdgcn_s_setprio(0);
    __builtin_amdgcn_s_barrier();

    // ---- phase 1: quadrant (0,1); prefetch halves 2,3
    READ_B(1, b1f, bc)
    if (pre) {
      gload16(src[2][0] + ko, bd + loff[2][0]);
      gload16(src[2][1] + ko, bd + loff[2][1]);
      gload16(src[3][0] + ko, bd + loff[3][0]);
      gload16(src[3][1] + ko, bd + loff[3][1]);
    }
    __builtin_amdgcn_s_barrier();
    LGKM0_FENCE
    __builtin_amdgcn_s_setprio(1);
    MFMA_Q(0, 1, b1f)
    __builtin_amdgcn_s_setprio(0);
    __builtin_amdgcn_s_barrier();

    // ---- phase 2: quadrant (1,1)
    READ_A(1, bc)
    __builtin_amdgcn_s_barrier();
    LGKM0_FENCE
    __builtin_amdgcn_s_setprio(1);
    MFMA_Q(1, 1, b1f)
    __builtin_amdgcn_s_setprio(0);
    __builtin_amdgcn_s_barrier();

    // ---- phase 3: quadrant (1,0); tile-boundary drain
    __builtin_amdgcn_s_setprio(1);
    MFMA_Q(1, 0, b0f)
    __builtin_amdgcn_s_setprio(0);
    asm volatile("s_waitcnt vmcnt(0)" ::: "memory");
    __builtin_amdgcn_s_barrier();
  }

  // ---- epilogue
#pragma unroll
  for (int am = 0; am < 8; am++) {
    int rowb = m0 + wm * 128 + (am >> 2) * 64 + (am & 3) * 16 + g * 4;
#pragma unroll
    for (int bn = 0; bn < 4; bn++) {
      int col = n0 + wn * 64 + (bn >> 1) * 32 + (bn & 1) * 16 + ln;
#pragma unroll
      for (int rr = 0; rr < 4; rr++) {
        float v = acc[am][bn][rr];
        if (MODE == 1) {
          v = 0.5f * v * (1.f + erff(v * 0.70710678118654752f));
          Hout[(size_t)(rowb + rr) * NB + col] = f2bf(v);
        } else {
          int pr = rowb + rr;
          atomicAdd(Out + (size_t)perm[pr] * NB + col, wgt[pr] * v);
        }
      }
    }
  }
}

extern "C" void kernel_launch(void* const* d_in, const int* in_sizes, int n_in,
                              void* d_out, int out_size, void* d_ws, size_t ws_size,
                              hipStream_t stream) {
  const float* x = (const float*)d_in[0];
  const float* wgate = (const float*)d_in[1];
  const float* w1 = (const float*)d_in[2];
  const float* w2 = (const float*)d_in[3];
  float* out = (float*)d_out;

  char* w = (char*)d_ws;
  float* probs = (float*)w;                 w += (size_t)N_TOK * 8 * 4;
  int* eids = (int*)w;                      w += (size_t)N_TOK * 2 * 4;
  float* ewts = (float*)w;                  w += (size_t)N_TOK * 2 * 4;
  int* meta = (int*)w;                      w += 512;
  int* perm = (int*)w;                      w += (size_t)MAXROWS * 4;
  float* pwgt = (float*)w;                  w += (size_t)MAXROWS * 4;
  unsigned short* xb = (unsigned short*)w;  w += (size_t)N_TOK * DDIM * 2;
  unsigned short* w1t = (unsigned short*)w; w += (size_t)NEXP * DDIM * FDIM * 2;
  unsigned short* w2t = (unsigned short*)w; w += (size_t)NEXP * DDIM * FDIM * 2;
  unsigned short* h = (unsigned short*)w;   w += (size_t)MAXROWS * FDIM * 2;

  hipMemsetAsync(d_out, 0, (size_t)out_size * 4, stream);
  hipMemsetAsync(perm, 0, (size_t)MAXROWS * 8, stream);  // perm + pwgt (adjacent)

  router_kernel<<<N_TOK, 64, 0, stream>>>(x, wgate, probs, eids, ewts);
  plan_kernel<<<1, 256, 0, stream>>>(probs, eids, out + 4194304, meta);
  scatter_kernel<<<16, 256, 0, stream>>>(eids, ewts, meta, perm, pwgt);
  convert_x_kernel<<<4096, 256, 0, stream>>>(x, xb);
  transpose_conv<<<dim3(64, 16, 8), 256, 0, stream>>>(w1, w1t, DDIM, FDIM);
  transpose_conv<<<dim3(16, 64, 8), 256, 0, stream>>>(w2, w2t, FDIM, DDIM);
  // GEMM1: rows x [1024] @ [1024 x 4096]/expert -> h (gelu, bf16). 40x16 tiles.
  gemm8p<DDIM, 1, 16, true, 1><<<MAXT * 16, 512, 0, stream>>>(
      xb, w1t, h, nullptr, perm, pwgt, meta + 24, meta + 96, FDIM);
  // GEMM2: rows x [4096] @ [4096 x 1024]/expert, split-K=4 -> atomic f32 out.
  gemm8p<FDIM, 4, 4, false, 2><<<MAXT * 16, 512, 0, stream>>>(
      h, w2t, nullptr, out, perm, pwgt, meta + 24, meta + 96, DDIM);
}